// Round 1
// baseline (1096.105 us; speedup 1.0000x reference)
//
#include <hip/hip_runtime.h>
#include <math.h>

#define NNODES 50000
#define NEDGES 400000
#define NGRAPHS 64

__device__ __forceinline__ float lrelu(float x){ return x >= 0.f ? x : 0.2f*x; }
__device__ __forceinline__ float eluf(float x){ return x > 0.f ? x : expm1f(x); }
__device__ __forceinline__ unsigned fenc(float f){ unsigned u=__float_as_uint(f); return (u&0x80000000u)? ~u : (u|0x80000000u); }
__device__ __forceinline__ float fdec(unsigned u){ return __uint_as_float((u&0x80000000u)? (u^0x80000000u) : ~u); }

// ---------------- CSR build ----------------
__global__ void k_hist(const int* __restrict__ ei, int* __restrict__ deg){
  int e = blockIdx.x*blockDim.x + threadIdx.x;
  if (e < NEDGES) atomicAdd(&deg[ei[NEDGES + e]], 1);
}
__global__ void k_scan1(const int* __restrict__ deg, int* __restrict__ part, int n){
  __shared__ int buf[256];
  int i = blockIdx.x*256 + threadIdx.x;
  buf[threadIdx.x] = (i<n)? deg[i] : 0;
  __syncthreads();
  for (int s=128; s>0; s>>=1){ if (threadIdx.x < s) buf[threadIdx.x]+=buf[threadIdx.x+s]; __syncthreads(); }
  if (threadIdx.x==0) part[blockIdx.x]=buf[0];
}
__global__ void k_scan2(const int* __restrict__ part, int* __restrict__ bpre, int* __restrict__ row_off_last, int nb){
  __shared__ int buf[256];
  int t = threadIdx.x;
  int v = (t<nb)? part[t] : 0;
  buf[t]=v; __syncthreads();
  for (int s=1;s<256;s<<=1){ int a = (t>=s)? buf[t-s]:0; __syncthreads(); buf[t]+=a; __syncthreads(); }
  if (t<nb) bpre[t] = buf[t]-v;
  if (t==255) row_off_last[0] = buf[255];
}
__global__ void k_scan3(const int* __restrict__ deg, const int* __restrict__ bpre, int* __restrict__ row_off, int n){
  __shared__ int buf[256];
  int t = threadIdx.x;
  int i = blockIdx.x*256 + t;
  int v = (i<n)? deg[i]:0;
  buf[t]=v; __syncthreads();
  for (int s=1;s<256;s<<=1){ int a=(t>=s)?buf[t-s]:0; __syncthreads(); buf[t]+=a; __syncthreads(); }
  if (i<n) row_off[i] = bpre[blockIdx.x] + buf[t]-v;
}
__global__ void k_scatter(const int* __restrict__ ei, const int* __restrict__ row_off,
                          int* __restrict__ cursor, int* __restrict__ csr_src){
  int e = blockIdx.x*blockDim.x + threadIdx.x;
  if (e < NEDGES){
    int s = ei[e], d = ei[NEDGES+e];
    int pos = row_off[d] + atomicAdd(&cursor[d],1);
    csr_src[pos] = s;
  }
}

// ---------------- GEMM: C[M,N] = A[M,K] @ W[K,N], f32 ----------------
// BM=128, BN=64, BK=16; 256 threads; each thread 8x4 outputs.
__global__ __launch_bounds__(256) void k_gemm(const float* __restrict__ A, const float* __restrict__ W,
                                              float* __restrict__ Cmat, int M, int K, int N){
  __shared__ __align__(16) float As[16][128];
  __shared__ __align__(16) float Bs[16][64];
  int tid = threadIdx.x;
  int tx = tid & 15, ty = tid >> 4;
  int n0 = blockIdx.x * 64;
  int m0 = blockIdx.y * 128;
  int a_row = tid >> 1, a_k = (tid & 1)*8;
  int b_k = tid >> 4, b_n = (tid & 15)*4;
  float acc[8][4];
  #pragma unroll
  for (int i=0;i<8;i++)
    #pragma unroll
    for (int j=0;j<4;j++) acc[i][j]=0.f;
  for (int k0=0;k0<K;k0+=16){
    int grow = m0 + a_row;
    float4 va = make_float4(0.f,0.f,0.f,0.f), vb = va;
    if (grow < M){
      const float* p = &A[(size_t)grow*K + k0 + a_k];
      va = *(const float4*)p; vb = *(const float4*)(p+4);
    }
    float4 w = *(const float4*)&W[(size_t)(k0+b_k)*N + n0 + b_n];
    __syncthreads();
    As[a_k+0][a_row]=va.x; As[a_k+1][a_row]=va.y; As[a_k+2][a_row]=va.z; As[a_k+3][a_row]=va.w;
    As[a_k+4][a_row]=vb.x; As[a_k+5][a_row]=vb.y; As[a_k+6][a_row]=vb.z; As[a_k+7][a_row]=vb.w;
    *(float4*)&Bs[b_k][b_n] = w;
    __syncthreads();
    #pragma unroll
    for (int kk=0;kk<16;kk++){
      float4 a0 = *(const float4*)&As[kk][ty*8];
      float4 a1 = *(const float4*)&As[kk][ty*8+4];
      float4 b  = *(const float4*)&Bs[kk][tx*4];
      float av[8] = {a0.x,a0.y,a0.z,a0.w,a1.x,a1.y,a1.z,a1.w};
      float bv[4] = {b.x,b.y,b.z,b.w};
      #pragma unroll
      for (int i=0;i<8;i++)
        #pragma unroll
        for (int j=0;j<4;j++) acc[i][j] = fmaf(av[i], bv[j], acc[i][j]);
    }
  }
  #pragma unroll
  for (int i=0;i<8;i++){
    int row = m0 + ty*8 + i;
    if (row < M){
      float4 o = make_float4(acc[i][0],acc[i][1],acc[i][2],acc[i][3]);
      *(float4*)&Cmat[(size_t)row*N + n0 + tx*4] = o;
    }
  }
}

// ---------------- per-node attention scores es/ed ----------------
template<int C>
__global__ void k_scores(const float* __restrict__ h, const float* __restrict__ as_,
                         const float* __restrict__ ad_, float* __restrict__ es, float* __restrict__ ed){
  constexpr int HC = 4*C;
  __shared__ float ls[HC];
  __shared__ float ld2[HC];
  int n = blockIdx.x, t = threadIdx.x;
  float v = h[(size_t)n*HC + t];
  ls[t] = v * as_[t]; ld2[t] = v * ad_[t];
  __syncthreads();
  int cc = t & (C-1);
  for (int s=C/2; s>0; s>>=1){
    if (cc < s){ ls[t]+=ls[t+s]; ld2[t]+=ld2[t+s]; }
    __syncthreads();
  }
  if (cc==0){ int hd = t / C; es[n*4+hd]=ls[t]; ed[n*4+hd]=ld2[t]; }
}

// ---------------- per-node GAT aggregation ----------------
template<int C, bool CONCAT>
__global__ void k_gat(const float* __restrict__ hfeat, const float* __restrict__ es,
                      const float* __restrict__ ed, const int* __restrict__ row_off,
                      const int* __restrict__ csr_src, const float* __restrict__ bias,
                      float* __restrict__ out){
  constexpr int HC = 4*C;
  constexpr int CHUNK = 32;
  __shared__ unsigned mu[4];
  __shared__ float edn[4];
  __shared__ float den[4];
  __shared__ int sbuf[CHUNK];
  __shared__ float exbuf[CHUNK][4];
  int n = blockIdx.x, t = threadIdx.x;
  int head = t / C;
  int start = row_off[n];
  int deg = row_off[n+1] - start;
  int ecnt = deg + 1;                 // + self loop
  if (t < 4){ mu[t] = fenc(-INFINITY); edn[t] = ed[n*4+t]; den[t]=0.f; }
  __syncthreads();
  // phase A: per-head max over incoming edge scores
  float lm0=-INFINITY,lm1=-INFINITY,lm2=-INFINITY,lm3=-INFINITY;
  for (int e=t; e<ecnt; e+=HC){
    int s = (e<deg)? csr_src[start+e] : n;
    float4 e4 = *(const float4*)&es[s*4];
    lm0 = fmaxf(lm0, lrelu(e4.x + edn[0]));
    lm1 = fmaxf(lm1, lrelu(e4.y + edn[1]));
    lm2 = fmaxf(lm2, lrelu(e4.z + edn[2]));
    lm3 = fmaxf(lm3, lrelu(e4.w + edn[3]));
  }
  if (t < ecnt){
    atomicMax(&mu[0], fenc(lm0));
    atomicMax(&mu[1], fenc(lm1));
    atomicMax(&mu[2], fenc(lm2));
    atomicMax(&mu[3], fenc(lm3));
  }
  __syncthreads();
  // phase B: unnormalized aggregation + denominator
  float acc = 0.f;
  for (int e0=0; e0<ecnt; e0+=CHUNK){
    int cnt = min(CHUNK, ecnt-e0);
    __syncthreads();
    if (t < cnt){ int e = e0+t; sbuf[t] = (e<deg)? csr_src[start+e] : n; }
    __syncthreads();
    for (int u=t; u<cnt*4; u+=HC){
      int k = u >> 2, hh = u & 3;
      int s = sbuf[k];
      float sc = lrelu(es[s*4+hh] + edn[hh]);
      exbuf[k][hh] = expf(sc - fdec(mu[hh]));
    }
    __syncthreads();
    for (int k=0;k<cnt;k++){
      int s = sbuf[k];
      acc = fmaf(exbuf[k][head], hfeat[(size_t)s*HC + t], acc);
    }
    if (t < 4){
      float ds=0.f;
      for (int k=0;k<cnt;k++) ds += exbuf[k][t];
      den[t]+=ds;
    }
  }
  __syncthreads();
  float r = acc / (den[head] + 1e-16f);
  if constexpr (CONCAT){
    out[(size_t)n*HC + t] = eluf(r + bias[t]);
  } else {
    __shared__ float rbuf[HC];
    rbuf[t] = r; __syncthreads();
    if (t < C){
      float s4 = rbuf[t] + rbuf[C+t] + rbuf[2*C+t] + rbuf[3*C+t];
      out[(size_t)n*C + t] = eluf(s4*0.25f + bias[t]);
    }
  }
}

// ---------------- pooling + linear head ----------------
__device__ __forceinline__ int lowerb(const int* a, int n, int v){
  int lo=0, hi=n;
  while (lo<hi){ int mid=(lo+hi)>>1; if (a[mid]<v) lo=mid+1; else hi=mid; }
  return lo;
}
__global__ void k_pool(const float* __restrict__ g3, const int* __restrict__ batch, float* __restrict__ pooled){
  int g = blockIdx.x, c = threadIdx.x; // 64 blocks x 128 threads
  int lo = lowerb(batch, NNODES, g);
  int hi = lowerb(batch, NNODES, g+1);
  float s = 0.f;
  for (int nn=lo; nn<hi; ++nn) s += g3[(size_t)nn*128 + c];
  int cnt = hi-lo;
  pooled[g*128+c] = s / fmaxf((float)cnt, 1.f);
}
__global__ void k_lin(const float* __restrict__ pooled, const float* __restrict__ Wlin,
                      const float* __restrict__ blin, float* __restrict__ out){
  int t = threadIdx.x;
  if (t < 640){
    int g = t/10, j = t%10;
    float s = blin[j];
    for (int c=0;c<128;c++) s = fmaf(pooled[g*128+c], Wlin[c*10+j], s);
    out[t] = s;
  }
}

extern "C" void kernel_launch(void* const* d_in, const int* in_sizes, int n_in,
                              void* d_out, int out_size, void* d_ws, size_t ws_size,
                              hipStream_t stream){
  (void)in_sizes; (void)n_in; (void)out_size; (void)ws_size;
  const float* x    = (const float*)d_in[0];
  const int*   ei   = (const int*)d_in[1];
  const int*   batch= (const int*)d_in[2];
  const float* W1   = (const float*)d_in[3];
  const float* as1  = (const float*)d_in[4];
  const float* ad1  = (const float*)d_in[5];
  const float* b1   = (const float*)d_in[6];
  const float* W2   = (const float*)d_in[7];
  const float* as2  = (const float*)d_in[8];
  const float* ad2  = (const float*)d_in[9];
  const float* b2   = (const float*)d_in[10];
  const float* W3   = (const float*)d_in[11];
  const float* as3  = (const float*)d_in[12];
  const float* ad3  = (const float*)d_in[13];
  const float* b3   = (const float*)d_in[14];
  const float* Wlin = (const float*)d_in[15];
  const float* blin = (const float*)d_in[16];
  float* out = (float*)d_out;

  char* ws = (char*)d_ws;
  size_t off = 0;
  auto alloc = [&](size_t bytes)->char*{ char* p = ws + off; off += (bytes + 255) & ~(size_t)255; return p; };
  int* csr_src = (int*)alloc((size_t)NEDGES*4);
  int* row_off = (int*)alloc((size_t)(NNODES+1)*4);
  int* deg     = (int*)alloc((size_t)NNODES*4);
  int* cursor  = (int*)alloc((size_t)NNODES*4);
  int* part    = (int*)alloc(256*4);
  int* bpre    = (int*)alloc(256*4);
  float* es    = (float*)alloc((size_t)NNODES*4*4);
  float* ed    = (float*)alloc((size_t)NNODES*4*4);
  float* S1    = (float*)alloc((size_t)NNODES*512*4);   // h3
  float* S2    = (float*)alloc((size_t)NNODES*256*4);   // h1 -> h2 -> g3
  float* S3    = (float*)alloc((size_t)NNODES*256*4);   // g1 -> g2
  float* pooled= (float*)alloc((size_t)NGRAPHS*128*4);

  hipMemsetAsync(deg, 0, (size_t)NNODES*4, stream);
  hipMemsetAsync(cursor, 0, (size_t)NNODES*4, stream);
  int nbE = (NEDGES+255)/256;
  int nbS = (NNODES+255)/256; // 196
  k_hist<<<nbE,256,0,stream>>>(ei, deg);
  k_scan1<<<nbS,256,0,stream>>>(deg, part, NNODES);
  k_scan2<<<1,256,0,stream>>>(part, bpre, row_off+NNODES, nbS);
  k_scan3<<<nbS,256,0,stream>>>(deg, bpre, row_off, NNODES);
  k_scatter<<<nbE,256,0,stream>>>(ei, row_off, cursor, csr_src);

  int mb = (NNODES+127)/128;
  // layer 1: 128 -> 64 (4 heads x 16), concat
  float* h1 = S2; float* g1 = S3;
  k_gemm<<<dim3(1,mb),256,0,stream>>>(x, W1, h1, NNODES, 128, 64);
  k_scores<16><<<NNODES,64,0,stream>>>(h1, as1, ad1, es, ed);
  k_gat<16,true><<<NNODES,64,0,stream>>>(h1, es, ed, row_off, csr_src, b1, g1);
  // layer 2: 64 -> 256 (4 heads x 64), concat
  float* h2 = S2; float* g2 = S3;
  k_gemm<<<dim3(4,mb),256,0,stream>>>(g1, W2, h2, NNODES, 64, 256);
  k_scores<64><<<NNODES,256,0,stream>>>(h2, as2, ad2, es, ed);
  k_gat<64,true><<<NNODES,256,0,stream>>>(h2, es, ed, row_off, csr_src, b2, g2);
  // layer 3: 256 -> 512 (4 heads x 128), mean heads
  float* h3 = S1; float* g3 = S2;
  k_gemm<<<dim3(8,mb),256,0,stream>>>(g2, W3, h3, NNODES, 256, 512);
  k_scores<128><<<NNODES,512,0,stream>>>(h3, as3, ad3, es, ed);
  k_gat<128,false><<<NNODES,512,0,stream>>>(h3, es, ed, row_off, csr_src, b3, g3);
  // pool + linear
  k_pool<<<NGRAPHS,128,0,stream>>>(g3, batch, pooled);
  k_lin<<<1,1024,0,stream>>>(pooled, Wlin, blin, out);
}